// Round 5
// baseline (220.649 us; speedup 1.0000x reference)
//
#include <hip/hip_runtime.h>
#include <hip/hip_bf16.h>
#include <hip/hip_fp16.h>

// Problem constants (match reference)
#define B_     8
#define L_     4096
#define DIN    256
#define DOUT   256
#define NGATE  1536   // 3*DOUT*2 dirs
#define KDIM   768    // 3*DIN (im2col window)
#define LP     (L_ + 2)
#define CHUNK  32
#define NCHUNK (L_ / CHUNK)

typedef short    short8   __attribute__((ext_vector_type(8)));
typedef __bf16   bf16x8   __attribute__((ext_vector_type(8)));
typedef float    floatx16 __attribute__((ext_vector_type(16)));
typedef _Float16 half4    __attribute__((ext_vector_type(4)));

__device__ __forceinline__ float fast_sigmoid(float x) {
    return __builtin_amdgcn_rcpf(1.f + __expf(-x));
}
__device__ __forceinline__ float fast_tanh(float x) {
    return 1.f - 2.f * __builtin_amdgcn_rcpf(1.f + __expf(2.f * x));
}
__device__ __forceinline__ unsigned short f2bf(float x) {
    unsigned u = __float_as_uint(x);
    u += 0x7FFF + ((u >> 16) & 1);   // RNE
    return (unsigned short)(u >> 16);
}
// Async global->LDS, 16B per lane. LDS dest = wave-uniform base + lane*16.
__device__ __forceinline__ void gload16(const unsigned short* g, unsigned short* l) {
    __builtin_amdgcn_global_load_lds((const __attribute__((address_space(1))) void*)g,
                                     (__attribute__((address_space(3))) void*)l,
                                     16, 0, 0);
}

// Native-layout gates addressing (32x32x16 MFMA C-layout) -------------------
// For batch b, time t, gate column n:
//   bm=b*16+(t>>8), wr=(t>>6)&3, msub=(t>>5)&1, g=(t>>3)&3, lanehi=(t>>2)&1, rr=t&3
//   nblk=n>>7, wcl=(n>>6)&1, nsub=(n>>5)&1, ncol=n&31
// flat = ((bm*12+nblk)*8 + wr*2+wcl)*4096 + nsub*2048 + msub*1024 + g*256
//        + lanehi*128 + ncol*4 + rr
// A lane's 4 accumulator regs in a group = 4 consecutive t -> one 8B store;
// 64 lanes of a store instruction cover 512 contiguous bytes.
__device__ __forceinline__ int gate_noff(int n) {
    return (n >> 7) * 32768 + ((n >> 6) & 1) * 4096 + ((n >> 5) & 1) * 2048 + (n & 31) * 4;
}
__device__ __forceinline__ int gate_toff(int b, int t) {
    return (b * 16 + (t >> 8)) * 393216 + ((t >> 6) & 3) * 8192
         + ((t >> 5) & 1) * 1024 + ((t >> 3) & 3) * 256 + ((t >> 2) & 1) * 128 + (t & 3);
}

// ---------------------------------------------------------------------------
// prep_all: fused prep_x (blocks [0,NXB)) + prep_w (blocks [NXB,..)).
#define NXB ((B_ * LP * 64 + 255) / 256)
#define NWB ((NGATE * KDIM + 255) / 256)
__global__ void prep_all(const float* __restrict__ x, unsigned short* __restrict__ Xp,
                         const float* __restrict__ Wf, const float* __restrict__ bf_,
                         const float* __restrict__ Wb, const float* __restrict__ bb,
                         unsigned short* __restrict__ Wc, float* __restrict__ bc) {
    if (blockIdx.x < NXB) {
        int idx = blockIdx.x * 256 + threadIdx.x;
        int row = idx >> 6;
        if (row >= B_ * LP) return;
        int c4 = (idx & 63) << 2;
        int b = row / LP, r = row - b * LP;
        float4 v = make_float4(0.f, 0.f, 0.f, 0.f);
        if (r >= 1 && r <= L_) {
            v = *(const float4*)(x + ((size_t)(b * L_ + (r - 1))) * DIN + c4);
        }
        ushort4 o = make_ushort4(f2bf(v.x), f2bf(v.y), f2bf(v.z), f2bf(v.w));
        *(ushort4*)(Xp + (size_t)row * DIN + c4) = o;
    } else {
        int gid = (blockIdx.x - NXB) * 256 + threadIdx.x;
        if (gid < NGATE) {
            bc[gid] = (gid < 768) ? bf_[gid] : bb[gid - 768];
        }
        if (gid >= NGATE * KDIM) return;
        int n = gid / KDIM, k = gid - n * KDIM;
        int s = k >> 8, ic = k & 255;
        const float* W = (n < 768) ? Wf : Wb;
        int oc = (n < 768) ? n : n - 768;
        float v = W[(size_t)oc * KDIM + ic * 3 + s];
        Wc[(size_t)n * KDIM + k] = f2bf(v);
    }
}

// ---------------------------------------------------------------------------
// gemm_gates: 256x128 tile, 512 threads (8 waves, 64x64 each), BK=64, now
// using 32x32x16 bf16 MFMA (higher measured ceiling: 2495 vs 2075 TF; half
// the MFMA instruction count per K-step at same LDS traffic).
__launch_bounds__(512)
__global__ void gemm_gates(const unsigned short* __restrict__ Xp,
                           const unsigned short* __restrict__ Wc,
                           const float* __restrict__ bc,
                           _Float16* __restrict__ gates) {
    __shared__ unsigned short As[256 * 64];   // 32 KB
    __shared__ unsigned short Bs[128 * 64];   // 16 KB
    const int tid  = threadIdx.x;
    const int lane = tid & 63, wave = tid >> 6;     // wave 0..7
    const int l31 = lane & 31, lhi = lane >> 5;
    const int wr = wave >> 1, wcl = wave & 1;       // wr 0..3 (m), wcl 0..1 (n)

    int flat = blockIdx.x;                 // 0..1535
    int xcd  = flat & 7;
    int slot = flat >> 3;                  // 0..191
    int bm   = xcd * 16 + slot / 12;       // 0..127 m-tile (256 rows each)
    int nblk = slot % 12;
    const int b  = bm >> 4;
    const int t0 = (bm & 15) << 8;
    const int n0 = nblk << 7;
    const unsigned short* Ab = Xp + (size_t)b * LP * DIN;

    // Per-lane inverse-swizzle source mapping (constant across k-steps).
    int rowA[4], cgA[4], rowB[2], cgB[2];
#pragma unroll
    for (int j = 0; j < 4; j++) {
        int G = (wave * 4 + j) * 64 + lane;      // A granule 0..2047
        rowA[j] = G >> 3;
        cgA[j]  = ((G & 7) ^ (rowA[j] & 7)) * 8;
    }
#pragma unroll
    for (int j = 0; j < 2; j++) {
        int G = (wave * 2 + j) * 64 + lane;      // B granule 0..1023
        rowB[j] = G >> 3;
        cgB[j]  = ((G & 7) ^ (rowB[j] & 7)) * 8;
    }

    floatx16 acc[2][2];
#pragma unroll
    for (int i = 0; i < 2; i++)
#pragma unroll
        for (int j = 0; j < 2; j++) acc[i][j] = (floatx16)0.f;

    for (int k0 = 0; k0 < KDIM; k0 += 64) {
        const int sh = k0 >> 8;        // time shift 0..2
        const int c0 = k0 & 255;       // column offset within DIN
#pragma unroll
        for (int j = 0; j < 4; j++)
            gload16(Ab + (size_t)(t0 + rowA[j] + sh) * DIN + c0 + cgA[j],
                    &As[(wave * 4 + j) * 512]);
#pragma unroll
        for (int j = 0; j < 2; j++)
            gload16(Wc + (size_t)(n0 + rowB[j]) * KDIM + k0 + cgB[j],
                    &Bs[(wave * 2 + j) * 512]);
        __syncthreads();
#pragma unroll
        for (int ks = 0; ks < 4; ks++) {       // K-slice of 16
            const int gsel = ks * 2 + lhi;     // granule for this lane's k-half
            short8 af[2], bfr[2];
#pragma unroll
            for (int ms = 0; ms < 2; ms++) {
                int row = wr * 64 + ms * 32 + l31;
                af[ms] = *(const short8*)&As[row * 64 + ((gsel ^ (row & 7)) << 3)];
            }
#pragma unroll
            for (int ns = 0; ns < 2; ns++) {
                int row = wcl * 64 + ns * 32 + l31;
                bfr[ns] = *(const short8*)&Bs[row * 64 + ((gsel ^ (row & 7)) << 3)];
            }
#pragma unroll
            for (int ms = 0; ms < 2; ms++)
#pragma unroll
                for (int ns = 0; ns < 2; ns++)
                    acc[ms][ns] = __builtin_amdgcn_mfma_f32_32x32x16_bf16(
                        __builtin_bit_cast(bf16x8, af[ms]),
                        __builtin_bit_cast(bf16x8, bfr[ns]),
                        acc[ms][ns], 0, 0, 0);
        }
        __syncthreads();
    }

    // Epilogue: bias + activation, native-layout 8B stores (512B/instr).
    const int cls = (nblk >> 1) % 3;           // block-uniform gate class
    _Float16* gb = gates + ((size_t)(bm * 12 + nblk) * 8 + wave) * 4096 + lane * 4;
#pragma unroll
    for (int ns = 0; ns < 2; ns++) {
        float bias = bc[n0 + wcl * 64 + ns * 32 + l31];
#pragma unroll
        for (int ms = 0; ms < 2; ms++) {
#pragma unroll
            for (int g = 0; g < 4; g++) {
                half4 hv;
#pragma unroll
                for (int rr = 0; rr < 4; rr++) {
                    float v = acc[ms][ns][g * 4 + rr] + bias;
                    v = (cls == 2) ? fast_tanh(v) : fast_sigmoid(v);
                    hv[rr] = (_Float16)v;
                }
                *(half4*)(gb + ns * 2048 + ms * 1024 + g * 256) = hv;
            }
        }
    }
}

// ---------------------------------------------------------------------------
// scan_chunks (phase A): thread = one channel, block = one (chunk,b,dir).
// Reads f,z in native layout (8B = 4 consecutive t), composes the chunk
// affine map c_out = P*c_in + W.
__global__ void scan_chunks(const _Float16* __restrict__ gates,
                            float2* __restrict__ PW) {
    const int d = threadIdx.x;                       // channel 0..255
    const int s = blockIdx.x, b = blockIdx.y, dir = blockIdx.z;
    const int onf = gate_noff(dir * 768 + d);
    const int onz = gate_noff(dir * 768 + 512 + d);
    float P = 1.f, W = 0.f;
    if (dir == 0) {
#pragma unroll
        for (int gi = 0; gi < 8; gi++) {
            int t = s * CHUNK + gi * 4;
            int ot = gate_toff(b, t);
            half4 f4 = *(const half4*)(gates + ot + onf);
            half4 z4 = *(const half4*)(gates + ot + onz);
#pragma unroll
            for (int u = 0; u < 4; u++) {
                float f = (float)f4[u], z = (float)z4[u];
                W = f * W + (1.f - f) * z;
                P *= f;
            }
        }
    } else {
#pragma unroll
        for (int gi = 7; gi >= 0; gi--) {
            int t = s * CHUNK + gi * 4;
            int ot = gate_toff(b, t);
            half4 f4 = *(const half4*)(gates + ot + onf);
            half4 z4 = *(const half4*)(gates + ot + onz);
#pragma unroll
            for (int u = 3; u >= 0; u--) {
                float f = (float)f4[u], z = (float)z4[u];
                W = f * W + (1.f - f) * z;
                P *= f;
            }
        }
    }
    PW[(((size_t)(dir * 8 + b)) * NCHUNK + s) * 256 + d] = make_float2(P, W);
}

// ---------------------------------------------------------------------------
// scan_seq (phase B): sequential scan over NCHUNK=128 chunks.
__global__ void scan_seq(const float2* __restrict__ PW, float* __restrict__ C0) {
    const int c = threadIdx.x;
    const int dir = blockIdx.x >> 3, b = blockIdx.x & 7;
    const size_t base = ((size_t)(dir * 8 + b)) * NCHUNK * 256 + c;
    float cc = 0.f;
    if (dir == 0) {
#pragma unroll 16
        for (int s = 0; s < NCHUNK; s++) {
            float2 pw = PW[base + (size_t)s * 256];
            C0[base + (size_t)s * 256] = cc;
            cc = pw.x * cc + pw.y;
        }
    } else {
#pragma unroll 16
        for (int s = NCHUNK - 1; s >= 0; s--) {
            float2 pw = PW[base + (size_t)s * 256];
            C0[base + (size_t)s * 256] = cc;
            cc = pw.x * cc + pw.y;
        }
    }
}

// ---------------------------------------------------------------------------
// scan_final (phase C): thread = one channel, block = one (chunk,b,dir).
// Replays the chunk from C0 into a 32KB LDS h-tile, ONE barrier, then 8
// fully-coalesced float4 stores per thread (wave writes a contiguous 1KB
// row segment).
__global__ void scan_final(const _Float16* __restrict__ gates,
                           const float* __restrict__ C0,
                           float* __restrict__ out) {
    __shared__ float hbuf[CHUNK][256];
    const int d = threadIdx.x;
    const int s = blockIdx.x, b = blockIdx.y, dir = blockIdx.z;
    const int onf = gate_noff(dir * 768 + d);
    const int ono = gate_noff(dir * 768 + 256 + d);
    const int onz = gate_noff(dir * 768 + 512 + d);
    float c = C0[(((size_t)(dir * 8 + b)) * NCHUNK + s) * 256 + d];
    float lh = 0.f, lc = 0.f;

    if (dir == 0) {
#pragma unroll
        for (int gi = 0; gi < 8; gi++) {
            int t = s * CHUNK + gi * 4;
            int ot = gate_toff(b, t);
            half4 f4 = *(const half4*)(gates + ot + onf);
            half4 o4 = *(const half4*)(gates + ot + ono);
            half4 z4 = *(const half4*)(gates + ot + onz);
#pragma unroll
            for (int u = 0; u < 4; u++) {
                float f = (float)f4[u], z = (float)z4[u];
                c = f * c + (1.f - f) * z;
                float h = c * (float)o4[u];
                hbuf[gi * 4 + u][d] = h;
                lh = h;
            }
        }
        lc = c;
    } else {
#pragma unroll
        for (int gg = 0; gg < 8; gg++) {
            int gi = 7 - gg;
            int t = s * CHUNK + gi * 4;
            int ot = gate_toff(b, t);
            half4 f4 = *(const half4*)(gates + ot + onf);
            half4 o4 = *(const half4*)(gates + ot + ono);
            half4 z4 = *(const half4*)(gates + ot + onz);
#pragma unroll
            for (int u = 3; u >= 0; u--) {
                float f = (float)f4[u], z = (float)z4[u];
                c = f * c + (1.f - f) * z;
                float h = c * (float)o4[u];
                hbuf[gi * 4 + u][d] = h;
                if (gg == 0 && u == 3) { lh = h; lc = c; }
            }
        }
    }
    if (s == NCHUNK - 1) {
        float* lasth = out + (size_t)B_ * L_ * (2 * DOUT);
        float* lastc = lasth + B_ * (2 * DOUT);
        lasth[b * 2 * DOUT + dir * DOUT + d] = lh;
        lastc[b * 2 * DOUT + dir * DOUT + d] = lc;
    }
    __syncthreads();

    const float* hb = &hbuf[0][0];
    const size_t obase = ((size_t)(b * L_) + s * CHUNK) * (2 * DOUT) + dir * DOUT;
#pragma unroll
    for (int i = 0; i < 8; i++) {
        int chunk = i * 256 + d;              // 0..2047
        int row = chunk >> 6;                 // t_local 0..31
        int col = (chunk & 63) * 4;           // 0..252
        *(float4*)&out[obase + (size_t)row * (2 * DOUT) + col] =
            *(const float4*)&hb[row * 256 + col];
    }
}

// ---------------------------------------------------------------------------
extern "C" void kernel_launch(void* const* d_in, const int* in_sizes, int n_in,
                              void* d_out, int out_size, void* d_ws, size_t ws_size,
                              hipStream_t stream) {
    const float* x   = (const float*)d_in[0];
    // d_in[1] = lengths (unused by the reference computation)
    const float* Wf  = (const float*)d_in[2];
    const float* bfv = (const float*)d_in[3];
    const float* Wb  = (const float*)d_in[4];
    const float* bbv = (const float*)d_in[5];

    char* ws = (char*)d_ws;
    // Workspace layout (bytes):
    //   Xp    bf16  B*(L+2)*256          = 16,785,408   (offset 0; dead after GEMM)
    //   Wc    bf16  1536*768             =  2,359,296   (offset 16,785,408)
    //   bc    f32   1536                 =      6,144   (offset 19,144,704)
    //   gates fp16  B*L*1536             = 100,663,296  (offset 19,150,848, native layout)
    //   PW    f32x2 2*8*128*256          =  4,194,304   (offset 0 — reuses Xp)
    //   C0    f32   2*8*128*256          =  2,097,152   (offset 4,194,304 — reuses Xp)
    unsigned short* Xp    = (unsigned short*)(ws);
    unsigned short* Wc    = (unsigned short*)(ws + 16785408);
    float*          bc    = (float*)(ws + 19144704);
    _Float16*       gates = (_Float16*)(ws + 19150848);
    float2*         PW    = (float2*)(ws);              // reuse Xp region
    float*          C0    = (float*)(ws + 4194304);     // reuse Xp region
    float*          out   = (float*)d_out;

    prep_all<<<NXB + NWB, 256, 0, stream>>>(x, Xp, Wf, bfv, Wb, bbv, Wc, bc);
    gemm_gates<<<1536, 512, 0, stream>>>(Xp, Wc, bc, gates);
    scan_chunks<<<dim3(NCHUNK, B_, 2), 256, 0, stream>>>(gates, PW);
    scan_seq<<<16, 256, 0, stream>>>(PW, C0);
    scan_final<<<dim3(NCHUNK, B_, 2), 256, 0, stream>>>(gates, C0, out);
}